// Round 10
// baseline (363.569 us; speedup 1.0000x reference)
//
#include <hip/hip_runtime.h>
#include <hip/hip_bf16.h>

// Conv2d NCHW, stride=1, pad=1, N=16, C=8, K=8, H=W=1024, 3x3, fp32 in/out.
// Round 10: round 9 + PINNED prefetch. R9's VGPR_Count=56 proved the compiler
// sank the next-tile loads to their use point (no latency hiding). Fixes:
//   (a) sched_barrier(0) right after load issue -> loads cannot sink,
//   (b) LOADT unconditional (clamped index) -> straight-line loop body so the
//       fence and compute share one scheduling region,
//   (c) s_setprio(1) around ds_read+MFMA cluster (2 blocks/CU out of phase).
// Success indicator: VGPR_Count jumps to ~96-128 (staged regs live across
// compute). MFMA implicit-GEMM math unchanged (absmax 0.031 verified 3x).

typedef __attribute__((ext_vector_type(8))) short short8;
typedef __attribute__((ext_vector_type(4))) float f32x4;

#define HH 1024
#define WW 1024
#define HWsz (1024*1024)
#define WB 128          // output cols per tile
#define HB 8            // output rows per tile
#define SROWS 10        // staged rows per tile
#define UROW 137        // 16B units per LDS row (136 + 1 pad)
#define TPR 34          // staging tiles per row
#define NTILES (SROWS*TPR)   // 340
#define NIT 8           // h-tiles per strip (block)
#define GX 8            // 1024/WB
#define NSTRIP 16       // 1024/(HB*NIT)
#define NBLK (GX*NSTRIP*16)  // 2048 = 8 XCD x 256

__device__ __forceinline__ int pk2(float a, float b) {
    __hip_bfloat162 h = __float22bfloat162_rn(make_float2(a, b));  // v_cvt_pk_bf16_f32
    return *reinterpret_cast<int*>(&h);
}
__device__ __forceinline__ unsigned short f2bf(float f) {
    unsigned u = __float_as_uint(f);
    return (unsigned short)((u + 0x7FFFu + ((u >> 16) & 1u)) >> 16);   // RNE
}

__global__ __launch_bounds__(512, 4) void conv3x3_mfma_pin(
    const float* __restrict__ x,      // [16][8][1024][1024]
    const float* __restrict__ wgt,    // [8][8][3][3]
    const float* __restrict__ bias,   // [8]
    float* __restrict__ out)          // [16][8][1024][1024]
{
    __shared__ int4 lds[2 * SROWS * UROW];

    const int tid  = threadIdx.x;
    const int lane = tid & 63;
    const int wv   = tid >> 6;        // wave 0..7 = output row within tile
    const int l15  = lane & 15;
    const int ch   = lane >> 4;

    // ---- XCD swizzle + decode: 2048 = 8 x 256 ----
    const unsigned bid  = blockIdx.x;
    const unsigned work = (bid & 7u) * (NBLK / 8u) + (bid >> 3);
    const int n     = (int)(work >> 7);          // /(GX*NSTRIP)
    const unsigned rem = work & 127u;
    const int wx    = (int)(rem >> 4);
    const int strip = (int)(rem & 15u);
    const int w0    = wx * WB;
    const int hbase = strip * (HB * NIT);        // strip*64

    const float* xn = x + (size_t)n * 8 * HWsz;

    // ---- per-lane tap -> LDS unit offsets ----
    const int t0  = ch;                          // taps 0..3 (MFMA 0)
    const int kh0 = (t0 >= 3) ? 1 : 0;
    const int kw0 = t0 - 3 * kh0;
    const int t1  = 4 + ch;                      // taps 4..7 (MFMA 1)
    const int kh1 = (t1 >= 6) ? 2 : 1;
    const int kw1 = t1 - 3 * kh1;
    const int off0 = kh0 * UROW + kw0 + 3;
    const int off1 = kh1 * UROW + kw1 + 3;
    const int off2 = 2 * UROW + 2 + 3;           // tap 8 (2,2)

    // ---- weight B-fragments (once per block) ----
    const int  coc = (l15 < 8) ? l15 : 7;
    const bool com = (l15 < 8);
    short8 b0, b1, b2;
    {
        const float* wp0 = wgt + coc * 72 + kh0 * 3 + kw0;
        const float* wp1 = wgt + coc * 72 + kh1 * 3 + kw1;
        const float* wp2 = wgt + coc * 72 + 2 * 3 + 2;
#pragma unroll
        for (int j = 0; j < 8; ++j) {
            b0[j] = (short)(com ? f2bf(wp0[j * 9]) : 0);
            b1[j] = (short)(com ? f2bf(wp1[j * 9]) : 0);
            b2[j] = (short)((com && ch == 0) ? f2bf(wp2[j * 9]) : 0);
        }
    }
    const float bv = com ? bias[l15] : 0.0f;

    // ---- staging constants (1 tile per thread, tid<340) ----
    const bool st   = (tid < NTILES);
    const int  srow = st ? (tid / TPR) : 0;
    const int  swt  = st ? (tid - srow * TPR) : 0;
    const int  gw0  = w0 - 4 + swt * 4;                     // mult of 4
    const bool wok  = ((unsigned)gw0 < (unsigned)WW);

    f32x4 v0, v1, v2, v3, v4, v5, v6, v7;

    auto LOADT = [&](int it) {
        if (st) {
            const int gh = hbase + it * HB - 1 + srow;
            if (wok && (unsigned)gh < (unsigned)HH) {
                const float* p = xn + (size_t)gh * WW + gw0;
                v0 = *reinterpret_cast<const f32x4*>(p + 0 * (size_t)HWsz);
                v1 = *reinterpret_cast<const f32x4*>(p + 1 * (size_t)HWsz);
                v2 = *reinterpret_cast<const f32x4*>(p + 2 * (size_t)HWsz);
                v3 = *reinterpret_cast<const f32x4*>(p + 3 * (size_t)HWsz);
                v4 = *reinterpret_cast<const f32x4*>(p + 4 * (size_t)HWsz);
                v5 = *reinterpret_cast<const f32x4*>(p + 5 * (size_t)HWsz);
                v6 = *reinterpret_cast<const f32x4*>(p + 6 * (size_t)HWsz);
                v7 = *reinterpret_cast<const f32x4*>(p + 7 * (size_t)HWsz);
            } else {
                v0 = v1 = v2 = v3 = v4 = v5 = v6 = v7 = (f32x4)0.0f;
            }
        }
    };

    auto WRITET = [&](int bufsel) {
        if (st) {
            int4* dst = &lds[bufsel * (SROWS * UROW) + srow * UROW + swt * 4];
#pragma unroll
            for (int q = 0; q < 4; ++q) {
                int4 pk;
                pk.x = pk2(v0[q], v1[q]);
                pk.y = pk2(v2[q], v3[q]);
                pk.z = pk2(v4[q], v5[q]);
                pk.w = pk2(v6[q], v7[q]);
                dst[q] = pk;
            }
        }
    };

    // ---- pipelined strip loop (straight-line body) ----
    LOADT(0);
    for (int it = 0; it < NIT; ++it) {
        WRITET(it & 1);                 // vmcnt wait happens here (compiler)
        __syncthreads();

        int nx = it + 1;                // unconditional prefetch, clamped:
        if (nx >= NIT) nx = NIT - 1;    // last iter re-loads L2-hot tile (or DCE'd)
        LOADT(nx);
        __builtin_amdgcn_sched_barrier(0);   // PIN: loads cannot sink past here

        const int4* B = &lds[(it & 1) * (SROWS * UROW)];
        f32x4 acc[8];
#pragma unroll
        for (int wt = 0; wt < 8; ++wt) {
            acc[wt].x = bv; acc[wt].y = bv; acc[wt].z = bv; acc[wt].w = bv;
        }
        const int ubase = wv * UROW + l15;
        __builtin_amdgcn_s_setprio(1);
#pragma unroll
        for (int wt = 0; wt < 8; ++wt) {
            const int u = ubase + wt * 16;
            short8 a0 = *reinterpret_cast<const short8*>(&B[u + off0]);
            short8 a1 = *reinterpret_cast<const short8*>(&B[u + off1]);
            short8 a2 = *reinterpret_cast<const short8*>(&B[u + off2]);
            f32x4 c = acc[wt];
            c = __builtin_amdgcn_mfma_f32_16x16x32_bf16(a0, b0, c, 0, 0, 0);
            c = __builtin_amdgcn_mfma_f32_16x16x32_bf16(a1, b1, c, 0, 0, 0);
            c = __builtin_amdgcn_mfma_f32_16x16x32_bf16(a2, b2, c, 0, 0, 0);
            acc[wt] = c;
        }
        __builtin_amdgcn_s_setprio(0);

        if (com) {
            float* op = out + ((size_t)n * 8 + l15) * HWsz
                            + (size_t)(hbase + it * HB + wv) * WW + w0 + ch * 4;
#pragma unroll
            for (int wt = 0; wt < 8; ++wt)
                *reinterpret_cast<float4*>(op + wt * 16) =
                    *reinterpret_cast<const float4*>(&acc[wt]);
        }
    }
}

extern "C" void kernel_launch(void* const* d_in, const int* in_sizes, int n_in,
                              void* d_out, int out_size, void* d_ws, size_t ws_size,
                              hipStream_t stream) {
    const float* x    = (const float*)d_in[0];
    const float* wgt  = (const float*)d_in[1];
    const float* bias = (const float*)d_in[2];
    float* out = (float*)d_out;

    dim3 grid(NBLK, 1, 1);
    dim3 block(512, 1, 1);
    conv3x3_mfma_pin<<<grid, block, 0, stream>>>(x, wgt, bias, out);
}

// Round 11
// 299.404 us; speedup vs baseline: 1.2143x; 1.2143x over previous
//
#include <hip/hip_runtime.h>
#include <hip/hip_bf16.h>

// Conv2d NCHW, stride=1, pad=1, N=16, C=8, K=8, H=W=1024, 3x3, fp32 in/out.
// Round 11: global_load_lds DMA staging (nothing to sink -> loads stay issued
// under compute), fp32-in-LDS with ci-major-per-instruction layout realized by
// per-lane GLOBAL address permutation (LDS dest stays linear, m173 pattern),
// then an LDS->LDS transpose pass producing the round-7-verified bf16
// ci-interleaved fragment layout, then the verified MFMA compute.
// Strip loop: 16 h-tiles per block; halo rows refetch L2-hot.
// 2 barriers/iter; barrier A's implicit vmcnt(0) = DMA completion wait.

typedef __attribute__((ext_vector_type(8))) short short8;
typedef __attribute__((ext_vector_type(4))) float f32x4;

#define HH 1024
#define WW 1024
#define HWsz (1024*1024)
#define WB 128          // output cols per tile
#define HB 8            // output rows per tile
#define SROWS 10        // staged input rows per tile
#define UROW 136        // bf16 16B-units per row (covers wlocal 0..135)
#define FPITCH 1088     // fp32 floats per staged row = 34 wgrp * 8 ci * 4
#define NIT 16          // h-tiles per block (strip)
#define NSITES (SROWS*UROW)   // 1360

__device__ __forceinline__ int pk2(float a, float b) {
    __hip_bfloat162 h = __float22bfloat162_rn(make_float2(a, b));  // v_cvt_pk_bf16_f32
    return *reinterpret_cast<int*>(&h);
}
__device__ __forceinline__ unsigned short f2bf(float f) {
    unsigned u = __float_as_uint(f);
    return (unsigned short)((u + 0x7FFFu + ((u >> 16) & 1u)) >> 16);   // RNE
}
__device__ __forceinline__ void gl_lds16(const float* g, float* l) {
    __builtin_amdgcn_global_load_lds(
        (const __attribute__((address_space(1))) void*)g,
        (__attribute__((address_space(3))) void*)l, 16, 0, 0);
}

__global__ __launch_bounds__(256) void conv3x3_dma(
    const float* __restrict__ x,      // [16][8][1024][1024]
    const float* __restrict__ wgt,    // [8][8][3][3]
    const float* __restrict__ bias,   // [8]
    float* __restrict__ out)          // [16][8][1024][1024]
{
    __shared__ float fplds[SROWS * FPITCH];   // 43520 B, DMA dest (fp32)
    __shared__ int4  bflds[NSITES];           // 21760 B, bf16 ci-interleaved

    const int tid  = threadIdx.x;
    const int lane = tid & 63;
    const int wv   = tid >> 6;        // wave 0..3
    const int l15  = lane & 15;
    const int ch   = lane >> 4;

    const int wx    = blockIdx.x;     // 0..7
    const int strip = blockIdx.y;     // 0..7
    const int n     = blockIdx.z;     // 0..15
    const int w0    = wx * WB;
    const int htbase = strip * NIT * HB;

    const float* xn = x + (size_t)n * 8 * HWsz;

    // ---- tap -> bf16-LDS unit offsets (verified r7/r8) ----
    const int t0  = ch;                       // taps 0..3 (MFMA 0)
    const int kh0 = (t0 >= 3) ? 1 : 0;
    const int kw0 = t0 - 3 * kh0;
    const int t1  = 4 + ch;                   // taps 4..7 (MFMA 1)
    const int kh1 = (t1 >= 6) ? 2 : 1;
    const int kw1 = t1 - 3 * kh1;
    const int off0 = kh0 * UROW + kw0 + 3;
    const int off1 = kh1 * UROW + kw1 + 3;
    const int off2 = 2 * UROW + 2 + 3;        // tap 8 (2,2)

    // ---- weight B-fragments (verified r7/r8) ----
    const int  coc = (l15 < 8) ? l15 : 7;
    const bool com = (l15 < 8);
    short8 b0, b1, b2;
    {
        const float* wp0 = wgt + coc * 72 + kh0 * 3 + kw0;
        const float* wp1 = wgt + coc * 72 + kh1 * 3 + kw1;
        const float* wp2 = wgt + coc * 72 + 2 * 3 + 2;
#pragma unroll
        for (int j = 0; j < 8; ++j) {
            b0[j] = (short)(com ? f2bf(wp0[j * 9]) : 0);
            b1[j] = (short)(com ? f2bf(wp1[j * 9]) : 0);
            b2[j] = (short)((com && ch == 0) ? f2bf(wp2[j * 9]) : 0);
        }
    }
    const float bv = com ? bias[l15] : 0.0f;

    // ---- staging lane constants ----
    const int sci_f = lane >> 3;      // full instr: ci-major (ci = lane/8)
    const int swg_f = lane & 7;       //              wgrp    (wg = lane%8)
    const int sci_p = lane >> 1;      // partial instr (16 lanes): ci = lane/2
    const int swg_p = lane & 1;

    // wave's staged rows: {2wv, 2wv+1} (+ {8+wv} for wv<2)
    auto STAGE = [&](int htile) {
        int rows[3];
        rows[0] = 2 * wv; rows[1] = 2 * wv + 1; rows[2] = 8 + wv;
        const int nr = (wv < 2) ? 3 : 2;
        for (int i = 0; i < nr; ++i) {
            const int row = rows[i];                  // wave-uniform
            int gh = htile - 1 + row;
            gh = (gh < 0) ? 0 : ((gh > HH - 1) ? HH - 1 : gh);
            const float* rowf = xn + (size_t)sci_f * HWsz + (size_t)gh * WW;
#pragma unroll
            for (int q = 0; q < 4; ++q) {             // 4 full instrs
                int gs = w0 - 4 + (q * 8 + swg_f) * 4;
                gs = (gs < 0) ? 0 : ((gs > WW - 4) ? WW - 4 : gs);
                gl_lds16(rowf + gs, &fplds[row * FPITCH + q * 256]);
            }
            if (lane < 16) {                          // partial instr (u 128..135)
                const float* rowp = xn + (size_t)sci_p * HWsz + (size_t)gh * WW;
                int gs = w0 - 4 + (32 + swg_p) * 4;
                gs = (gs > WW - 4) ? WW - 4 : gs;
                gl_lds16(rowp + gs, &fplds[row * FPITCH + 1024]);
            }
        }
    };

    STAGE(htbase);                                    // prologue: tile 0

    for (int it = 0; it < NIT; ++it) {
        const int htile = htbase + it * HB;
        __syncthreads();   // A: implicit vmcnt(0) -> DMA for this tile landed

        // ---- transpose pass: fp32 [ci-major blocks] -> bf16 [w][ci] ----
        for (int s = tid; s < NSITES; s += 256) {
            const int row = s / UROW;
            const int u   = s - row * UROW;
            const int gh  = htile - 1 + row;
            const int gw  = w0 - 4 + u;
            const bool ok = ((unsigned)gh < (unsigned)HH) &&
                            ((unsigned)gw < (unsigned)WW);
            int fbase, cs;
            if (u < 128) {
                fbase = row * FPITCH + (u >> 5) * 256 + ((u >> 2) & 7) * 4 + (u & 3);
                cs = 32;
            } else {
                fbase = row * FPITCH + 1024 + ((u >> 2) & 1) * 4 + (u & 3);
                cs = 8;
            }
            float v0 = ok ? fplds[fbase]          : 0.0f;
            float v1 = ok ? fplds[fbase + 1 * cs] : 0.0f;
            float v2 = ok ? fplds[fbase + 2 * cs] : 0.0f;
            float v3 = ok ? fplds[fbase + 3 * cs] : 0.0f;
            float v4 = ok ? fplds[fbase + 4 * cs] : 0.0f;
            float v5 = ok ? fplds[fbase + 5 * cs] : 0.0f;
            float v6 = ok ? fplds[fbase + 6 * cs] : 0.0f;
            float v7 = ok ? fplds[fbase + 7 * cs] : 0.0f;
            int4 pk;
            pk.x = pk2(v0, v1);
            pk.y = pk2(v2, v3);
            pk.z = pk2(v4, v5);
            pk.w = pk2(v6, v7);
            bflds[s] = pk;                            // s == row*UROW + u
        }
        __syncthreads();   // B: bf16 tile ready; fp32 buffer free

        if (it + 1 < NIT) STAGE(htile + HB);          // DMA flies under compute

        // ---- compute: wave wv owns h-rows 2wv, 2wv+1 (verified r7) ----
        f32x4 acc[2][8];
#pragma unroll
        for (int th = 0; th < 2; ++th)
#pragma unroll
            for (int wt = 0; wt < 8; ++wt) {
                acc[th][wt].x = bv; acc[th][wt].y = bv;
                acc[th][wt].z = bv; acc[th][wt].w = bv;
            }
#pragma unroll
        for (int th = 0; th < 2; ++th) {
            const int hl = wv * 2 + th;
            const int ub = hl * UROW + l15;
#pragma unroll
            for (int wt = 0; wt < 8; ++wt) {
                const int u = ub + wt * 16;
                short8 a0 = *reinterpret_cast<const short8*>(&bflds[u + off0]);
                short8 a1 = *reinterpret_cast<const short8*>(&bflds[u + off1]);
                short8 a2 = *reinterpret_cast<const short8*>(&bflds[u + off2]);
                f32x4 c = acc[th][wt];
                c = __builtin_amdgcn_mfma_f32_16x16x32_bf16(a0, b0, c, 0, 0, 0);
                c = __builtin_amdgcn_mfma_f32_16x16x32_bf16(a1, b1, c, 0, 0, 0);
                c = __builtin_amdgcn_mfma_f32_16x16x32_bf16(a2, b2, c, 0, 0, 0);
                acc[th][wt] = c;
            }
        }

        // ---- store (verified r7/r9) ----
        if (com) {
#pragma unroll
            for (int th = 0; th < 2; ++th) {
                const int hl = wv * 2 + th;
                float* op = out + ((size_t)n * 8 + l15) * HWsz
                                + (size_t)(htile + hl) * WW + w0 + ch * 4;
#pragma unroll
                for (int wt = 0; wt < 8; ++wt)
                    *reinterpret_cast<float4*>(op + wt * 16) =
                        *reinterpret_cast<const float4*>(&acc[th][wt]);
            }
        }
    }
}

extern "C" void kernel_launch(void* const* d_in, const int* in_sizes, int n_in,
                              void* d_out, int out_size, void* d_ws, size_t ws_size,
                              hipStream_t stream) {
    const float* x    = (const float*)d_in[0];
    const float* wgt  = (const float*)d_in[1];
    const float* bias = (const float*)d_in[2];
    float* out = (float*)d_out;

    dim3 grid(8, 8, 16);    // (wx, strip, n) = 1024 blocks
    dim3 block(256, 1, 1);
    conv3x3_dma<<<grid, block, 0, stream>>>(x, wgt, bias, out);
}